// Round 1
// 681.621 us; speedup vs baseline: 1.1691x; 1.1691x over previous
//
#include <hip/hip_runtime.h>
#include <hip/hip_bf16.h>

typedef __bf16 v8bf16 __attribute__((ext_vector_type(8)));
typedef float  v4f32  __attribute__((ext_vector_type(4)));

static __device__ __forceinline__ float leaky(float v) { return v >= 0.0f ? v : 0.01f * v; }
static __device__ __forceinline__ float bfbits2f(unsigned short b) {
    union { unsigned u; float f; } c; c.u = ((unsigned)b) << 16; return c.f;
}
static __device__ __forceinline__ unsigned short f2bfbits(float f) {
    __hip_bfloat16 h = __float2bfloat16(f);
    unsigned short s; __builtin_memcpy(&s, &h, 2); return s;
}

// ---------------------------------------------------------------------------
// Weight transpose+cvt: W[K][N] fp32 -> Wt[N][K] bf16  (for small GEMMs)
// ---------------------------------------------------------------------------
__global__ void transpose_cvt(const float* __restrict__ W,
                              __hip_bfloat16* __restrict__ Wt, int K, int N) {
    int i = blockIdx.x * 256 + threadIdx.x;
    if (i >= K * N) return;
    int r = i / N, c = i % N;
    Wt[c * K + r] = __float2bfloat16(W[i]);
}

// ---------------------------------------------------------------------------
// W1 -> MFMA-fragment-ordered bf16 layout for gemm_enc1.
// ---------------------------------------------------------------------------
__global__ void prep_frag(const float* __restrict__ W, __hip_bfloat16* __restrict__ out,
                          int K, int N, int total) {
    int tid = blockIdx.x * 256 + threadIdx.x;
    if (tid >= total) return;
    int j = tid & 7, l = (tid >> 3) & 63, G = tid >> 9;
    int m = l & 15, q = l >> 4;
    int t = G & 7, kk = G >> 3;
    int n = t * 16 + m;
    int k = kk * 32 + q * 8 + j;
    out[tid] = __float2bfloat16(W[k * N + n]);
}

__global__ void zero_u32(unsigned* __restrict__ p, int n) {
    int i = blockIdx.x * 256 + threadIdx.x;
    if (i < n) p[i] = 0u;
}

// ---------------------------------------------------------------------------
// CSR build via hierarchical bucketing (replaces deg_rank + node-scan +
// fill_csr, which were bound by per-edge global atomic write-through:
// 3.2M random 32B RMW sectors = ~112 MB HBM writes each).
// Buckets: 256 dst-nodes per bucket (bucket = dst >> 8), NB = ceil(NN/256).
// Packed edge word: src | (dst&255)<<20  (needs NN < 2^20).
// ---------------------------------------------------------------------------
constexpr int EPB = 12800;  // edges per partition block

// Pass A: global bucket histogram (LDS-privatized; ~NB global atomics/block).
__global__ __launch_bounds__(256) void bucket_count(const int* __restrict__ dst,
                                                    unsigned* __restrict__ bcnt,
                                                    int E, int NB) {
    __shared__ unsigned hist[512];
    const int tid = threadIdx.x;
    hist[tid] = 0u; hist[tid + 256] = 0u;
    __syncthreads();
    const int beg = blockIdx.x * EPB;
    const int end = min(beg + EPB, E);
    for (int e = beg + tid; e < end; e += 256)
        atomicAdd(&hist[((unsigned)dst[e]) >> 8], 1u);
    __syncthreads();
    if (tid < NB) { unsigned v = hist[tid]; if (v) atomicAdd(&bcnt[tid], v); }
    const int t2 = tid + 256;
    if (t2 < NB) { unsigned v = hist[t2]; if (v) atomicAdd(&bcnt[t2], v); }
}

// Pass B0: exclusive scan of bucket counts -> bases; init reservation cursors.
__global__ __launch_bounds__(512) void bucket_scan(const unsigned* __restrict__ bcnt,
                                                   unsigned* __restrict__ bases,
                                                   unsigned* __restrict__ bcur, int NB) {
    __shared__ unsigned ts[512];
    const int tid = threadIdx.x;
    unsigned v = (tid < NB) ? bcnt[tid] : 0u;
    ts[tid] = v;
    __syncthreads();
    for (int off = 1; off < 512; off <<= 1) {
        unsigned t = (tid >= off) ? ts[tid - off] : 0u;
        __syncthreads();
        ts[tid] += t;
        __syncthreads();
    }
    const unsigned excl = ts[tid] - v;
    if (tid < NB) { bases[tid] = excl; bcur[tid] = excl; }
    if (tid == NB - 1) bases[NB] = ts[tid];
}

// Pass B: partition edges into bucket-grouped array. Per block: LDS hist +
// scan, ONE global atomic per nonempty bucket to reserve space, LDS-staged
// reorder (edge indices), coalesced run write-out of packed words.
__global__ __launch_bounds__(512) void bucket_scatter(
    const int* __restrict__ src, const int* __restrict__ dst,
    unsigned* __restrict__ bcur, unsigned* __restrict__ ebuck, int E, int NB) {
    __shared__ unsigned stg[EPB];
    __shared__ unsigned hist[512], inc[512], cur[512], start[512];
    const int tid = threadIdx.x;
    hist[tid] = 0u;
    __syncthreads();
    const int beg = blockIdx.x * EPB;
    const int end = min(beg + EPB, E);
    for (int e = beg + tid; e < end; e += 512)
        atomicAdd(&hist[((unsigned)dst[e]) >> 8], 1u);
    __syncthreads();
    const unsigned h = hist[tid];
    inc[tid] = h;
    __syncthreads();
    for (int off = 1; off < 512; off <<= 1) {
        unsigned t = (tid >= off) ? inc[tid - off] : 0u;
        __syncthreads();
        inc[tid] += t;
        __syncthreads();
    }
    cur[tid] = inc[tid] - h;  // exclusive (mutable cursor)
    if (tid < NB && h > 0u) start[tid] = atomicAdd(&bcur[tid], h);
    __syncthreads();
    // stage edge indices grouped by bucket
    for (int e = beg + tid; e < end; e += 512) {
        unsigned b = ((unsigned)dst[e]) >> 8;
        unsigned r = atomicAdd(&cur[b], 1u);
        stg[r] = (unsigned)e;
    }
    __syncthreads();
    const int cnt = end - beg;
    for (int s = tid; s < cnt; s += 512) {
        const unsigned e = stg[s];
        const unsigned d = (unsigned)dst[e];
        const unsigned b = d >> 8;
        const unsigned excl = inc[b] - hist[b];
        const unsigned pos = start[b] + ((unsigned)s - excl);
        ebuck[pos] = (unsigned)src[e] | ((d & 255u) << 20);
    }
}

// Pass C: one block per bucket. LDS per-node histogram -> deg/dinv/rowptr
// (coalesced), LDS-atomic rank -> CSR fill into a 32KB L2-resident window.
__global__ __launch_bounds__(256) void bucket_csr(
    const unsigned* __restrict__ bases, const unsigned* __restrict__ ebuck,
    unsigned* __restrict__ rowptr, float* __restrict__ dinv,
    int* __restrict__ csr, int NN) {
    __shared__ unsigned hist[256], cur[256];
    const int tid = threadIdx.x;
    const int k = blockIdx.x;
    const unsigned bbase = bases[k], bend = bases[k + 1];
    hist[tid] = 0u;
    __syncthreads();
    for (unsigned e = bbase + tid; e < bend; e += 256)
        atomicAdd(&hist[ebuck[e] >> 20], 1u);
    __syncthreads();
    const unsigned h = hist[tid];
    cur[tid] = h;
    __syncthreads();
    for (int off = 1; off < 256; off <<= 1) {
        unsigned t = (tid >= off) ? cur[tid - off] : 0u;
        __syncthreads();
        cur[tid] += t;
        __syncthreads();
    }
    const unsigned excl = cur[tid] - h;
    const int node = k * 256 + tid;
    if (node < NN) {
        rowptr[node] = bbase + excl;
        if (node == NN - 1) rowptr[NN] = bbase + excl + h;
        dinv[node] = rsqrtf((float)(h + 1u));  // +1 self-loop
    }
    __syncthreads();
    cur[tid] = excl;
    __syncthreads();
    for (unsigned e = bbase + tid; e < bend; e += 256) {
        const unsigned pk = ebuck[e];
        const unsigned pos = bbase + atomicAdd(&cur[pk >> 20], 1u);
        csr[pos] = (int)(pk & 0xFFFFFu);
    }
}

// ---------------------------------------------------------------------------
// GEMM1 (encoder layer 1): C[M,128] = leaky(A[M,512]@W1 + b1), A fp32.
// ---------------------------------------------------------------------------
__global__ __launch_bounds__(256, 4) void gemm_enc1(
    const float* __restrict__ A, const uint4* __restrict__ Bp,
    const float* __restrict__ bias, __hip_bfloat16* __restrict__ C, int M) {
    constexpr int K = 512;
    __shared__ uint4 lds[2][1024];  // 2 x 16 KB
    const int tid = threadIdx.x;
    const int wid = tid >> 6, lane = tid & 63;
    const int m = lane & 15, q = lane >> 4;
    const int row0 = blockIdx.x * 64 + wid * 16;
    const int rowA = row0 + m;
    const int rowAc = rowA < M ? rowA : M - 1;
    const float* Ap = A + (size_t)rowAc * K + q * 8;

    v4f32 acc[8];
#pragma unroll
    for (int t = 0; t < 8; t++) acc[t] = (v4f32){0.f, 0.f, 0.f, 0.f};

    float4 ab[2][4];

    auto loadA = [&](int c, int par) {
#pragma unroll
        for (int j = 0; j < 4; j++)
            ab[par][j] = *reinterpret_cast<const float4*>(Ap + c * 64 + (j >> 1) * 32 + (j & 1) * 4);
    };
    auto stage = [&](int c, int par) {
#pragma unroll
        for (int r = 0; r < 4; r++)
            lds[par][r * 256 + tid] = Bp[c * 1024 + r * 256 + tid];
    };

    stage(0, 0);
    loadA(0, 0);
    for (int c = 0; c < 8; c++) {
        __syncthreads();
        if (c < 7) { stage(c + 1, (c + 1) & 1); loadA(c + 1, (c + 1) & 1); }
        const int par = c & 1;
#pragma unroll
        for (int kk2 = 0; kk2 < 2; kk2++) {
            float4 f0 = ab[par][kk2 * 2], f1 = ab[par][kk2 * 2 + 1];
            v8bf16 a = {(__bf16)f0.x, (__bf16)f0.y, (__bf16)f0.z, (__bf16)f0.w,
                        (__bf16)f1.x, (__bf16)f1.y, (__bf16)f1.z, (__bf16)f1.w};
#pragma unroll
            for (int t = 0; t < 8; t++) {
                v8bf16 b = reinterpret_cast<const v8bf16*>(lds[par])[(kk2 * 8 + t) * 64 + lane];
                acc[t] = __builtin_amdgcn_mfma_f32_16x16x32_bf16(a, b, acc[t], 0, 0, 0);
            }
        }
    }

#pragma unroll
    for (int r = 0; r < 4; r++) {
        const int row = row0 + q * 4 + r;
        if (row >= M) continue;
#pragma unroll
        for (int t = 0; t < 8; t++) {
            const int col = t * 16 + m;
            C[(size_t)row * 128 + col] = __float2bfloat16(leaky(acc[t][r] + bias[col]));
        }
    }
}

// ---------------------------------------------------------------------------
// Small GEMM (bf16 A): C[M,N] = A[M,K]@B, Bt[N][K] bf16.
// MODE 0: C=bf16(leaky(AB+bias));  MODE 1: C=bf16((AB)*dinv[row])
// ---------------------------------------------------------------------------
template <int NT, int MODE>
__global__ __launch_bounds__(256) void gemm_kernel(
    const __hip_bfloat16* __restrict__ A, const __hip_bfloat16* __restrict__ Bt,
    const float* __restrict__ bias, const float* __restrict__ dinv,
    __hip_bfloat16* __restrict__ Cbf, int M, int K) {
    const int wid  = threadIdx.x >> 6;
    const int lane = threadIdx.x & 63;
    const int row0 = (blockIdx.x * 4 + wid) << 4;
    if (row0 >= M) return;
    const int m = lane & 15, q = lane >> 4;

    const __hip_bfloat16* Ab = A + (size_t)(row0 + m) * K + q * 8;

    v4f32 acc[NT];
#pragma unroll
    for (int t = 0; t < NT; t++) acc[t] = (v4f32){0.f, 0.f, 0.f, 0.f};

    for (int k0 = 0; k0 < K; k0 += 32) {
        v8bf16 a = *reinterpret_cast<const v8bf16*>(Ab + k0);
#pragma unroll
        for (int t = 0; t < NT; t++) {
            v8bf16 b = *reinterpret_cast<const v8bf16*>(Bt + (size_t)(t * 16 + m) * K + k0 + q * 8);
            acc[t] = __builtin_amdgcn_mfma_f32_16x16x32_bf16(a, b, acc[t], 0, 0, 0);
        }
    }

    const int N = NT * 16;
#pragma unroll
    for (int r = 0; r < 4; r++) {
        const int row = row0 + q * 4 + r;
        float di = (MODE == 1) ? dinv[row] : 1.0f;
#pragma unroll
        for (int t = 0; t < NT; t++) {
            const int col = t * 16 + m;
            float v = acc[t][r];
            if (MODE == 0) v = leaky(v + bias[col]);
            else           v *= di;
            Cbf[(size_t)row * N + col] = __float2bfloat16(v);
        }
    }
}

// ---------------------------------------------------------------------------
// Fused CSR gather + GCN epilogue. One wave per dst node.
// ---------------------------------------------------------------------------
template <int HEAD>
__global__ __launch_bounds__(256) void gather_kernel(
    const unsigned* __restrict__ rowptr, const int* __restrict__ csr_src,
    const __hip_bfloat16* __restrict__ u, const float* __restrict__ dinv,
    const float* __restrict__ bias, __hip_bfloat16* __restrict__ out_bf,
    float* __restrict__ out_h, const float* __restrict__ Wc,
    const float* __restrict__ bc, float* __restrict__ out_logits, int n) {
    const int node = blockIdx.x * 4 + (threadIdx.x >> 6);
    if (node >= n) return;
    const int lane = threadIdx.x & 63;
    const int g = lane >> 4, t = lane & 15;
    const unsigned beg = rowptr[node], end = rowptr[node + 1];

    float s0 = 0.f, s1 = 0.f, s2 = 0.f, s3 = 0.f;
    for (unsigned e = beg + g; e < end; e += 4) {
        int sidx = csr_src[e];
        ushort4 w = *reinterpret_cast<const ushort4*>(u + (size_t)sidx * 64 + t * 4);
        s0 += bfbits2f(w.x); s1 += bfbits2f(w.y); s2 += bfbits2f(w.z); s3 += bfbits2f(w.w);
    }
    s0 += __shfl_xor(s0, 16, 64); s1 += __shfl_xor(s1, 16, 64);
    s2 += __shfl_xor(s2, 16, 64); s3 += __shfl_xor(s3, 16, 64);
    s0 += __shfl_xor(s0, 32, 64); s1 += __shfl_xor(s1, 32, 64);
    s2 += __shfl_xor(s2, 32, 64); s3 += __shfl_xor(s3, 32, 64);

    ushort4 ws = *reinterpret_cast<const ushort4*>(u + (size_t)node * 64 + t * 4);
    s0 += bfbits2f(ws.x); s1 += bfbits2f(ws.y); s2 += bfbits2f(ws.z); s3 += bfbits2f(ws.w);

    const float di = dinv[node];
    const int f0i = t * 4;
    float f0 = leaky(s0 * di + bias[f0i + 0]);
    float f1 = leaky(s1 * di + bias[f0i + 1]);
    float f2 = leaky(s2 * di + bias[f0i + 2]);
    float f3 = leaky(s3 * di + bias[f0i + 3]);

    if (HEAD == 0) {
        if (g == 0) {
            ushort4 o = {f2bfbits(f0), f2bfbits(f1), f2bfbits(f2), f2bfbits(f3)};
            *reinterpret_cast<ushort4*>(out_bf + (size_t)node * 64 + f0i) = o;
        }
    } else {
        if (g == 0) {
            float4 o = {f0, f1, f2, f3};
            *reinterpret_cast<float4*>(out_h + (size_t)node * 64 + f0i) = o;
        }
        float p0 = f0 * Wc[(f0i + 0) * 2] + f1 * Wc[(f0i + 1) * 2] +
                   f2 * Wc[(f0i + 2) * 2] + f3 * Wc[(f0i + 3) * 2];
        float p1 = f0 * Wc[(f0i + 0) * 2 + 1] + f1 * Wc[(f0i + 1) * 2 + 1] +
                   f2 * Wc[(f0i + 2) * 2 + 1] + f3 * Wc[(f0i + 3) * 2 + 1];
#pragma unroll
        for (int o = 8; o; o >>= 1) {
            p0 += __shfl_xor(p0, o, 64);
            p1 += __shfl_xor(p1, o, 64);
        }
        if (lane == 0) {
            out_logits[(size_t)node * 2 + 0] = p0 + bc[0];
            out_logits[(size_t)node * 2 + 1] = p1 + bc[1];
        }
    }
}

// ---------------------------------------------------------------------------
extern "C" void kernel_launch(void* const* d_in, const int* in_sizes, int n_in,
                              void* d_out, int out_size, void* d_ws, size_t ws_size,
                              hipStream_t stream) {
    const float* x   = (const float*)d_in[0];
    const int*   ei  = (const int*)d_in[1];
    const float* W1  = (const float*)d_in[2];
    const float* b1  = (const float*)d_in[3];
    const float* W2  = (const float*)d_in[4];
    const float* b2  = (const float*)d_in[5];
    const float* Wg1 = (const float*)d_in[6];
    const float* bg1 = (const float*)d_in[7];
    const float* Wg2 = (const float*)d_in[8];
    const float* bg2 = (const float*)d_in[9];
    const float* Wc  = (const float*)d_in[10];
    const float* bc  = (const float*)d_in[11];

    const int DH  = in_sizes[3];            // 128
    const int DIN = in_sizes[2] / DH;       // 512
    const int NN  = in_sizes[0] / DIN;      // 100000
    const int E   = in_sizes[1] / 2;        // 3200000
    const int DO  = in_sizes[5];            // 64
    const int* src = ei;
    const int* dst = ei + E;

    // workspace layout (~91 MB total)
    char*  ws  = (char*)d_ws;
    size_t off = 0;
    auto alloc = [&](size_t bytes) {
        void* p = ws + off;
        off += (bytes + 255) & ~(size_t)255;
        return p;
    };
    __hip_bfloat16* h1    = (__hip_bfloat16*)alloc((size_t)NN * DH * 2);
    __hip_bfloat16* h2    = (__hip_bfloat16*)alloc((size_t)NN * DO * 2);
    __hip_bfloat16* h3    = (__hip_bfloat16*)alloc((size_t)NN * DO * 2);
    __hip_bfloat16* ub    = (__hip_bfloat16*)alloc((size_t)NN * DO * 2);
    float*          dinv  = (float*)alloc((size_t)NN * 4);
    unsigned*       rowp  = (unsigned*)alloc(((size_t)NN + 1) * 4);
    int*            csr   = (int*)alloc((size_t)E * 4);
    unsigned*       ebuck = (unsigned*)alloc((size_t)E * 4);
    unsigned*       bcnt  = (unsigned*)alloc(512 * 4);
    unsigned*       bases = (unsigned*)alloc(513 * 4);
    unsigned*       bcur  = (unsigned*)alloc(512 * 4);
    __hip_bfloat16* W1f   = (__hip_bfloat16*)alloc((size_t)DIN * DH * 2);
    __hip_bfloat16* W2t   = (__hip_bfloat16*)alloc((size_t)DH * DO * 2);
    __hip_bfloat16* Wg1t  = (__hip_bfloat16*)alloc((size_t)DO * DO * 2);
    __hip_bfloat16* Wg2t  = (__hip_bfloat16*)alloc((size_t)DO * DO * 2);

    float* out_logits = (float*)d_out;
    float* out_h      = (float*)d_out + (size_t)NN * 2;

    // 1. weight prep
    prep_frag<<<(DIN * DH + 255) / 256, 256, 0, stream>>>(W1, W1f, DIN, DH, DIN * DH);
    transpose_cvt<<<(DH * DO + 255) / 256, 256, 0, stream>>>(W2, W2t, DH, DO);
    transpose_cvt<<<(DO * DO + 255) / 256, 256, 0, stream>>>(Wg1, Wg1t, DO, DO);
    transpose_cvt<<<(DO * DO + 255) / 256, 256, 0, stream>>>(Wg2, Wg2t, DO, DO);

    // 2. CSR build via bucket partition (no per-edge global atomics)
    const int NB    = (NN + 255) >> 8;          // 391 buckets of 256 nodes
    const int nblkP = (E + EPB - 1) / EPB;      // 250 partition blocks
    zero_u32<<<(NB + 255) / 256, 256, 0, stream>>>(bcnt, NB);
    bucket_count<<<nblkP, 256, 0, stream>>>(dst, bcnt, E, NB);
    bucket_scan<<<1, 512, 0, stream>>>(bcnt, bases, bcur, NB);
    bucket_scatter<<<nblkP, 512, 0, stream>>>(src, dst, bcur, ebuck, E, NB);
    bucket_csr<<<NB, 256, 0, stream>>>(bases, ebuck, rowp, dinv, csr, NN);

    const int gemm_blocks = (NN / 16 + 3) / 4;

    // 3. encoder
    gemm_enc1<<<(NN + 63) / 64, 256, 0, stream>>>(x, (const uint4*)W1f, b1, h1, NN);
    gemm_kernel<4, 0><<<gemm_blocks, 256, 0, stream>>>(h1, W2t, b2, nullptr, h2, NN, DH);

    // 4. GCN layer 1: u = (h2@Wg1)*dinv ; gather+epilogue -> h3 (bf16)
    gemm_kernel<4, 1><<<gemm_blocks, 256, 0, stream>>>(h2, Wg1t, nullptr, dinv, ub, NN, DO);
    gather_kernel<0><<<(NN + 3) / 4, 256, 0, stream>>>(rowp, csr, ub, dinv, bg1, h3,
                                                       nullptr, nullptr, nullptr, nullptr, NN);

    // 5. GCN layer 2 + head
    gemm_kernel<4, 1><<<gemm_blocks, 256, 0, stream>>>(h3, Wg2t, nullptr, dinv, ub, NN, DO);
    gather_kernel<1><<<(NN + 3) / 4, 256, 0, stream>>>(rowp, csr, ub, dinv, bg2, nullptr,
                                                       out_h, Wc, bc, out_logits, NN);
}

// Round 2
// 595.460 us; speedup vs baseline: 1.3382x; 1.1447x over previous
//
#include <hip/hip_runtime.h>
#include <hip/hip_bf16.h>

typedef __bf16 v8bf16 __attribute__((ext_vector_type(8)));
typedef float  v4f32  __attribute__((ext_vector_type(4)));
typedef unsigned short ushort8v __attribute__((ext_vector_type(8)));

static __device__ __forceinline__ float leaky(float v) { return v >= 0.0f ? v : 0.01f * v; }
static __device__ __forceinline__ float bfbits2f(unsigned short b) {
    union { unsigned u; float f; } c; c.u = ((unsigned)b) << 16; return c.f;
}
static __device__ __forceinline__ unsigned short f2bfbits(float f) {
    __hip_bfloat16 h = __float2bfloat16(f);
    unsigned short s; __builtin_memcpy(&s, &h, 2); return s;
}

// ---------------------------------------------------------------------------
// W1 -> MFMA-fragment-ordered bf16 layout for gemm_enc1.
// ---------------------------------------------------------------------------
__global__ void prep_frag(const float* __restrict__ W, __hip_bfloat16* __restrict__ out,
                          int K, int N, int total) {
    int tid = blockIdx.x * 256 + threadIdx.x;
    if (tid >= total) return;
    int j = tid & 7, l = (tid >> 3) & 63, G = tid >> 9;
    int m = l & 15, q = l >> 4;
    int t = G & 7, kk = G >> 3;
    int n = t * 16 + m;
    int k = kk * 32 + q * 8 + j;
    out[tid] = __float2bfloat16(W[k * N + n]);
}

// ---------------------------------------------------------------------------
// Fused small-weight transpose+cvt: W2[DH][DO], Wg1[DO][DO], Wg2[DO][DO]
// ---------------------------------------------------------------------------
__global__ void prep_small(const float* __restrict__ W2, const float* __restrict__ Wg1,
                           const float* __restrict__ Wg2, __hip_bfloat16* __restrict__ W2t,
                           __hip_bfloat16* __restrict__ Wg1t, __hip_bfloat16* __restrict__ Wg2t,
                           int DH, int DO) {
    const int n2 = DH * DO, ng = DO * DO;
    int i = blockIdx.x * 256 + threadIdx.x;
    if (i < n2) {
        int r = i / DO, c = i % DO;
        W2t[c * DH + r] = __float2bfloat16(W2[i]);
    } else if (i < n2 + ng) {
        int j = i - n2; int r = j / DO, c = j % DO;
        Wg1t[c * DO + r] = __float2bfloat16(Wg1[j]);
    } else if (i < n2 + 2 * ng) {
        int j = i - n2 - ng; int r = j / DO, c = j % DO;
        Wg2t[c * DO + r] = __float2bfloat16(Wg2[j]);
    }
}

__global__ void zero_u32(unsigned* __restrict__ p, int n) {
    int i = blockIdx.x * 256 + threadIdx.x;
    if (i < n) p[i] = 0u;
}

// ---------------------------------------------------------------------------
// CSR build via hierarchical bucketing with fixed-capacity bucket regions.
// Buckets: 256 dst-nodes (bucket = dst >> 8), NB = ceil(NN/256) = 391.
// Region k = ebuck[k*BCAP .. ]. Mean load 8184, BCAP=16384 (~90 sigma safe).
// Packed edge word: src | (dst&255)<<20  (needs NN < 2^20).
// ---------------------------------------------------------------------------
constexpr int EPB  = 6400;   // edges per partition block
constexpr int BCAP = 16384;  // per-bucket region capacity

// Pass A: partition edges into per-bucket regions. Per block: LDS hist+scan,
// one global atomic per nonempty bucket to reserve region space, LDS-staged
// reorder, coalesced-run write-out of packed words. bcur[k] ends = count(k).
__global__ __launch_bounds__(512) void bucket_scatter(
    const int* __restrict__ src, const int* __restrict__ dst,
    unsigned* __restrict__ bcur, unsigned* __restrict__ ebuck, int E, int NB) {
    __shared__ unsigned stg[EPB];
    __shared__ unsigned hist[512], inc[512], cur[512], start[512];
    const int tid = threadIdx.x;
    hist[tid] = 0u;
    __syncthreads();
    const int beg = blockIdx.x * EPB;
    const int end = min(beg + EPB, E);
    for (int e = beg + tid; e < end; e += 512)
        atomicAdd(&hist[((unsigned)dst[e]) >> 8], 1u);
    __syncthreads();
    const unsigned h = hist[tid];
    inc[tid] = h;
    __syncthreads();
    for (int off = 1; off < 512; off <<= 1) {
        unsigned t = (tid >= off) ? inc[tid - off] : 0u;
        __syncthreads();
        inc[tid] += t;
        __syncthreads();
    }
    cur[tid] = inc[tid] - h;  // exclusive (mutable cursor)
    if (tid < NB && h > 0u)
        start[tid] = (unsigned)tid * BCAP + atomicAdd(&bcur[tid], h);
    __syncthreads();
    // stage edge indices grouped by bucket
    for (int e = beg + tid; e < end; e += 512) {
        unsigned b = ((unsigned)dst[e]) >> 8;
        unsigned r = atomicAdd(&cur[b], 1u);
        stg[r] = (unsigned)e;
    }
    __syncthreads();
    const int cnt = end - beg;
    for (int s = tid; s < cnt; s += 512) {
        const unsigned e = stg[s];
        const unsigned d = (unsigned)dst[e];
        const unsigned b = d >> 8;
        const unsigned excl = inc[b] - hist[b];
        const unsigned pos = start[b] + ((unsigned)s - excl);
        ebuck[pos] = (unsigned)src[e] | ((d & 255u) << 20);
    }
}

// Pass B: exclusive scan of bucket counts -> global bases for rowptr/csr.
__global__ __launch_bounds__(512) void bucket_scan(const unsigned* __restrict__ bcnt,
                                                   unsigned* __restrict__ bases, int NB) {
    __shared__ unsigned ts[512];
    const int tid = threadIdx.x;
    unsigned v = (tid < NB) ? bcnt[tid] : 0u;
    ts[tid] = v;
    __syncthreads();
    for (int off = 1; off < 512; off <<= 1) {
        unsigned t = (tid >= off) ? ts[tid - off] : 0u;
        __syncthreads();
        ts[tid] += t;
        __syncthreads();
    }
    if (tid < NB) {
        bases[tid] = ts[tid] - v;
        if (tid == NB - 1) bases[NB] = ts[tid];
    }
}

// Pass C: one block per bucket. LDS per-node histogram -> dinv/rowptr
// (coalesced), LDS-atomic rank -> CSR fill into a 32KB L2-resident window.
__global__ __launch_bounds__(256) void bucket_csr(
    const unsigned* __restrict__ bases, const unsigned* __restrict__ bcnt,
    const unsigned* __restrict__ ebuck, unsigned* __restrict__ rowptr,
    float* __restrict__ dinv, int* __restrict__ csr, int NN) {
    __shared__ unsigned hist[256], cur[256];
    const int tid = threadIdx.x;
    const int k = blockIdx.x;
    const unsigned cntb = bcnt[k];
    const unsigned base = bases[k];
    const unsigned* eb = ebuck + (size_t)k * BCAP;
    hist[tid] = 0u;
    __syncthreads();
    for (unsigned e = tid; e < cntb; e += 256)
        atomicAdd(&hist[eb[e] >> 20], 1u);
    __syncthreads();
    const unsigned h = hist[tid];
    cur[tid] = h;
    __syncthreads();
    for (int off = 1; off < 256; off <<= 1) {
        unsigned t = (tid >= off) ? cur[tid - off] : 0u;
        __syncthreads();
        cur[tid] += t;
        __syncthreads();
    }
    const unsigned excl = cur[tid] - h;
    const int node = k * 256 + tid;
    if (node < NN) {
        rowptr[node] = base + excl;
        if (node == NN - 1) rowptr[NN] = base + excl + h;
        dinv[node] = rsqrtf((float)(h + 1u));  // +1 self-loop
    }
    __syncthreads();
    cur[tid] = excl;
    __syncthreads();
    for (unsigned e = tid; e < cntb; e += 256) {
        const unsigned pk = eb[e];
        const unsigned pos = base + atomicAdd(&cur[pk >> 20], 1u);
        csr[pos] = (int)(pk & 0xFFFFFu);
    }
}

// ---------------------------------------------------------------------------
// GEMM1 (encoder layer 1): C[M,128] = leaky(A[M,512]@W1 + b1), A fp32.
// ---------------------------------------------------------------------------
__global__ __launch_bounds__(256, 4) void gemm_enc1(
    const float* __restrict__ A, const uint4* __restrict__ Bp,
    const float* __restrict__ bias, __hip_bfloat16* __restrict__ C, int M) {
    constexpr int K = 512;
    __shared__ uint4 lds[2][1024];  // 2 x 16 KB
    const int tid = threadIdx.x;
    const int wid = tid >> 6, lane = tid & 63;
    const int m = lane & 15, q = lane >> 4;
    const int row0 = blockIdx.x * 64 + wid * 16;
    const int rowA = row0 + m;
    const int rowAc = rowA < M ? rowA : M - 1;
    const float* Ap = A + (size_t)rowAc * K + q * 8;

    v4f32 acc[8];
#pragma unroll
    for (int t = 0; t < 8; t++) acc[t] = (v4f32){0.f, 0.f, 0.f, 0.f};

    float4 ab[2][4];

    auto loadA = [&](int c, int par) {
#pragma unroll
        for (int j = 0; j < 4; j++)
            ab[par][j] = *reinterpret_cast<const float4*>(Ap + c * 64 + (j >> 1) * 32 + (j & 1) * 4);
    };
    auto stage = [&](int c, int par) {
#pragma unroll
        for (int r = 0; r < 4; r++)
            lds[par][r * 256 + tid] = Bp[c * 1024 + r * 256 + tid];
    };

    stage(0, 0);
    loadA(0, 0);
    for (int c = 0; c < 8; c++) {
        __syncthreads();
        if (c < 7) { stage(c + 1, (c + 1) & 1); loadA(c + 1, (c + 1) & 1); }
        const int par = c & 1;
#pragma unroll
        for (int kk2 = 0; kk2 < 2; kk2++) {
            float4 f0 = ab[par][kk2 * 2], f1 = ab[par][kk2 * 2 + 1];
            v8bf16 a = {(__bf16)f0.x, (__bf16)f0.y, (__bf16)f0.z, (__bf16)f0.w,
                        (__bf16)f1.x, (__bf16)f1.y, (__bf16)f1.z, (__bf16)f1.w};
#pragma unroll
            for (int t = 0; t < 8; t++) {
                v8bf16 b = reinterpret_cast<const v8bf16*>(lds[par])[(kk2 * 8 + t) * 64 + lane];
                acc[t] = __builtin_amdgcn_mfma_f32_16x16x32_bf16(a, b, acc[t], 0, 0, 0);
            }
        }
    }

#pragma unroll
    for (int r = 0; r < 4; r++) {
        const int row = row0 + q * 4 + r;
        if (row >= M) continue;
#pragma unroll
        for (int t = 0; t < 8; t++) {
            const int col = t * 16 + m;
            C[(size_t)row * 128 + col] = __float2bfloat16(leaky(acc[t][r] + bias[col]));
        }
    }
}

// ---------------------------------------------------------------------------
// Small GEMM (bf16 A): C[M,N] = A[M,K]@B, Bt[N][K] bf16.
// MODE 0: C=bf16(leaky(AB+bias));  MODE 1: C=bf16((AB)*dinv[row])
// ---------------------------------------------------------------------------
template <int NT, int MODE>
__global__ __launch_bounds__(256) void gemm_kernel(
    const __hip_bfloat16* __restrict__ A, const __hip_bfloat16* __restrict__ Bt,
    const float* __restrict__ bias, const float* __restrict__ dinv,
    __hip_bfloat16* __restrict__ Cbf, int M, int K) {
    const int wid  = threadIdx.x >> 6;
    const int lane = threadIdx.x & 63;
    const int row0 = (blockIdx.x * 4 + wid) << 4;
    if (row0 >= M) return;
    const int m = lane & 15, q = lane >> 4;

    const __hip_bfloat16* Ab = A + (size_t)(row0 + m) * K + q * 8;

    v4f32 acc[NT];
#pragma unroll
    for (int t = 0; t < NT; t++) acc[t] = (v4f32){0.f, 0.f, 0.f, 0.f};

    for (int k0 = 0; k0 < K; k0 += 32) {
        v8bf16 a = *reinterpret_cast<const v8bf16*>(Ab + k0);
#pragma unroll
        for (int t = 0; t < NT; t++) {
            v8bf16 b = *reinterpret_cast<const v8bf16*>(Bt + (size_t)(t * 16 + m) * K + k0 + q * 8);
            acc[t] = __builtin_amdgcn_mfma_f32_16x16x32_bf16(a, b, acc[t], 0, 0, 0);
        }
    }

    const int N = NT * 16;
#pragma unroll
    for (int r = 0; r < 4; r++) {
        const int row = row0 + q * 4 + r;
        float di = (MODE == 1) ? dinv[row] : 1.0f;
#pragma unroll
        for (int t = 0; t < NT; t++) {
            const int col = t * 16 + m;
            float v = acc[t][r];
            if (MODE == 0) v = leaky(v + bias[col]);
            else           v *= di;
            Cbf[(size_t)row * N + col] = __float2bfloat16(v);
        }
    }
}

// ---------------------------------------------------------------------------
// Fused CSR gather + GCN epilogue. One wave per dst node.
// 8 groups x 8 lanes: 8 edge-rows in flight per wave (16B/lane loads),
// next-index software prefetch overlaps the gather latency.
// ---------------------------------------------------------------------------
template <int HEAD>
__global__ __launch_bounds__(256) void gather_kernel(
    const unsigned* __restrict__ rowptr, const int* __restrict__ csr_src,
    const __hip_bfloat16* __restrict__ u, const float* __restrict__ dinv,
    const float* __restrict__ bias, __hip_bfloat16* __restrict__ out_bf,
    float* __restrict__ out_h, const float* __restrict__ Wc,
    const float* __restrict__ bc, float* __restrict__ out_logits, int n) {
    const int node = blockIdx.x * 4 + (threadIdx.x >> 6);
    if (node >= n) return;
    const int lane = threadIdx.x & 63;
    const int g = lane >> 3, t = lane & 7;  // 8 groups x 8 lanes
    const unsigned beg = rowptr[node], end = rowptr[node + 1];

    float s[8];
#pragma unroll
    for (int j = 0; j < 8; j++) s[j] = 0.f;

    unsigned e = beg + g;
    bool have = e < end;
    int sidx = have ? csr_src[e] : 0;
    while (have) {
        const unsigned en = e + 8;
        const bool hn = en < end;
        const int sn = hn ? csr_src[en] : 0;
        ushort8v w = *reinterpret_cast<const ushort8v*>(u + (size_t)sidx * 64 + t * 8);
#pragma unroll
        for (int j = 0; j < 8; j++) s[j] += bfbits2f(w[j]);
        e = en; sidx = sn; have = hn;
    }
    // reduce across the 8 groups (lane bits 3,4,5)
#pragma unroll
    for (int j = 0; j < 8; j++) {
        s[j] += __shfl_xor(s[j], 8, 64);
        s[j] += __shfl_xor(s[j], 16, 64);
        s[j] += __shfl_xor(s[j], 32, 64);
    }

    // self-loop row
    ushort8v wsr = *reinterpret_cast<const ushort8v*>(u + (size_t)node * 64 + t * 8);
#pragma unroll
    for (int j = 0; j < 8; j++) s[j] += bfbits2f(wsr[j]);

    const float di = dinv[node];
    const float4 b0 = *reinterpret_cast<const float4*>(bias + t * 8);
    const float4 b1 = *reinterpret_cast<const float4*>(bias + t * 8 + 4);
    float f[8];
    f[0] = leaky(s[0] * di + b0.x); f[1] = leaky(s[1] * di + b0.y);
    f[2] = leaky(s[2] * di + b0.z); f[3] = leaky(s[3] * di + b0.w);
    f[4] = leaky(s[4] * di + b1.x); f[5] = leaky(s[5] * di + b1.y);
    f[6] = leaky(s[6] * di + b1.z); f[7] = leaky(s[7] * di + b1.w);

    if (HEAD == 0) {
        if (g == 0) {
            ushort8v o;
#pragma unroll
            for (int j = 0; j < 8; j++) o[j] = f2bfbits(f[j]);
            *reinterpret_cast<ushort8v*>(out_bf + (size_t)node * 64 + t * 8) = o;
        }
    } else {
        if (g == 0) {
            float4 o0 = {f[0], f[1], f[2], f[3]};
            float4 o1 = {f[4], f[5], f[6], f[7]};
            *reinterpret_cast<float4*>(out_h + (size_t)node * 64 + t * 8) = o0;
            *reinterpret_cast<float4*>(out_h + (size_t)node * 64 + t * 8 + 4) = o1;
        }
        float p0 = 0.f, p1 = 0.f;
#pragma unroll
        for (int j = 0; j < 8; j++) {
            p0 += f[j] * Wc[(t * 8 + j) * 2];
            p1 += f[j] * Wc[(t * 8 + j) * 2 + 1];
        }
#pragma unroll
        for (int o = 4; o; o >>= 1) {
            p0 += __shfl_xor(p0, o, 64);
            p1 += __shfl_xor(p1, o, 64);
        }
        if (lane == 0) {
            out_logits[(size_t)node * 2 + 0] = p0 + bc[0];
            out_logits[(size_t)node * 2 + 1] = p1 + bc[1];
        }
    }
}

// ---------------------------------------------------------------------------
extern "C" void kernel_launch(void* const* d_in, const int* in_sizes, int n_in,
                              void* d_out, int out_size, void* d_ws, size_t ws_size,
                              hipStream_t stream) {
    const float* x   = (const float*)d_in[0];
    const int*   ei  = (const int*)d_in[1];
    const float* W1  = (const float*)d_in[2];
    const float* b1  = (const float*)d_in[3];
    const float* W2  = (const float*)d_in[4];
    const float* b2  = (const float*)d_in[5];
    const float* Wg1 = (const float*)d_in[6];
    const float* bg1 = (const float*)d_in[7];
    const float* Wg2 = (const float*)d_in[8];
    const float* bg2 = (const float*)d_in[9];
    const float* Wc  = (const float*)d_in[10];
    const float* bc  = (const float*)d_in[11];

    const int DH  = in_sizes[3];            // 128
    const int DIN = in_sizes[2] / DH;       // 512
    const int NN  = in_sizes[0] / DIN;      // 100000
    const int E   = in_sizes[1] / 2;        // 3200000
    const int DO  = in_sizes[5];            // 64
    const int* src = ei;
    const int* dst = ei + E;

    // workspace layout (~105 MB total)
    char*  ws  = (char*)d_ws;
    size_t off = 0;
    auto alloc = [&](size_t bytes) {
        void* p = ws + off;
        off += (bytes + 255) & ~(size_t)255;
        return p;
    };
    const int NB = (NN + 255) >> 8;  // 391 buckets
    __hip_bfloat16* h1    = (__hip_bfloat16*)alloc((size_t)NN * DH * 2);
    __hip_bfloat16* h2    = (__hip_bfloat16*)alloc((size_t)NN * DO * 2);
    __hip_bfloat16* h3    = (__hip_bfloat16*)alloc((size_t)NN * DO * 2);
    __hip_bfloat16* ub    = (__hip_bfloat16*)alloc((size_t)NN * DO * 2);
    float*          dinv  = (float*)alloc((size_t)NN * 4);
    unsigned*       rowp  = (unsigned*)alloc(((size_t)NN + 1) * 4);
    int*            csr   = (int*)alloc((size_t)E * 4);
    unsigned*       ebuck = (unsigned*)alloc((size_t)NB * BCAP * 4);
    unsigned*       bcur  = (unsigned*)alloc(512 * 4);
    unsigned*       bases = (unsigned*)alloc(513 * 4);
    __hip_bfloat16* W1f   = (__hip_bfloat16*)alloc((size_t)DIN * DH * 2);
    __hip_bfloat16* W2t   = (__hip_bfloat16*)alloc((size_t)DH * DO * 2);
    __hip_bfloat16* Wg1t  = (__hip_bfloat16*)alloc((size_t)DO * DO * 2);
    __hip_bfloat16* Wg2t  = (__hip_bfloat16*)alloc((size_t)DO * DO * 2);

    float* out_logits = (float*)d_out;
    float* out_h      = (float*)d_out + (size_t)NN * 2;

    // 1. weight prep
    prep_frag<<<(DIN * DH + 255) / 256, 256, 0, stream>>>(W1, W1f, DIN, DH, DIN * DH);
    prep_small<<<(DH * DO + 2 * DO * DO + 255) / 256, 256, 0, stream>>>(
        W2, Wg1, Wg2, W2t, Wg1t, Wg2t, DH, DO);

    // 2. CSR build (fixed-capacity bucket regions, no global per-edge atomics)
    const int nblkP = (E + EPB - 1) / EPB;  // 500 partition blocks
    zero_u32<<<(NB + 255) / 256, 256, 0, stream>>>(bcur, NB);
    bucket_scatter<<<nblkP, 512, 0, stream>>>(src, dst, bcur, ebuck, E, NB);
    bucket_scan<<<1, 512, 0, stream>>>(bcur, bases, NB);
    bucket_csr<<<NB, 256, 0, stream>>>(bases, bcur, ebuck, rowp, dinv, csr, NN);

    const int gemm_blocks = (NN / 16 + 3) / 4;

    // 3. encoder
    gemm_enc1<<<(NN + 63) / 64, 256, 0, stream>>>(x, (const uint4*)W1f, b1, h1, NN);
    gemm_kernel<4, 0><<<gemm_blocks, 256, 0, stream>>>(h1, W2t, b2, nullptr, h2, NN, DH);

    // 4. GCN layer 1: u = (h2@Wg1)*dinv ; gather+epilogue -> h3 (bf16)
    gemm_kernel<4, 1><<<gemm_blocks, 256, 0, stream>>>(h2, Wg1t, nullptr, dinv, ub, NN, DO);
    gather_kernel<0><<<(NN + 3) / 4, 256, 0, stream>>>(rowp, csr, ub, dinv, bg1, h3,
                                                       nullptr, nullptr, nullptr, nullptr, NN);

    // 5. GCN layer 2 + head
    gemm_kernel<4, 1><<<gemm_blocks, 256, 0, stream>>>(h3, Wg2t, nullptr, dinv, ub, NN, DO);
    gather_kernel<1><<<(NN + 3) / 4, 256, 0, stream>>>(rowp, csr, ub, dinv, bg2, nullptr,
                                                       out_h, Wc, bc, out_logits, NN);
}

// Round 3
// 557.098 us; speedup vs baseline: 1.4304x; 1.0689x over previous
//
#include <hip/hip_runtime.h>
#include <hip/hip_bf16.h>

typedef __bf16 v8bf16 __attribute__((ext_vector_type(8)));
typedef float  v4f32  __attribute__((ext_vector_type(4)));
typedef unsigned short ushort8v __attribute__((ext_vector_type(8)));

static __device__ __forceinline__ float leaky(float v) { return v >= 0.0f ? v : 0.01f * v; }
static __device__ __forceinline__ float bfbits2f(unsigned short b) {
    union { unsigned u; float f; } c; c.u = ((unsigned)b) << 16; return c.f;
}
static __device__ __forceinline__ unsigned short f2bfbits(float f) {
    __hip_bfloat16 h = __float2bfloat16(f);
    unsigned short s; __builtin_memcpy(&s, &h, 2); return s;
}

// ---------------------------------------------------------------------------
// CSR build constants: buckets of 256 dst nodes, fixed-capacity padded
// regions (mean load 8184, BCAP=16384 ~ 90 sigma for uniform random dst).
// ebuck word: src | (dst&255)<<20  (needs NN < 2^20).
// csr uses the SAME padded layout (bucket k at k*BCAP) -> no global scan.
// ---------------------------------------------------------------------------
constexpr int EPB  = 6400;
constexpr int BCAP = 16384;

// ---------------------------------------------------------------------------
// L1: fused weight prep + bcur zero.
// role A: W1 -> MFMA-fragment-ordered bf16 (for enc1)
// role B: W2/Wg1/Wg2 transpose+cvt
// role C: zero bucket cursors
// ---------------------------------------------------------------------------
__global__ __launch_bounds__(256) void prep_all(
    const float* __restrict__ W1, const float* __restrict__ W2,
    const float* __restrict__ Wg1, const float* __restrict__ Wg2,
    __hip_bfloat16* __restrict__ W1f, __hip_bfloat16* __restrict__ W2t,
    __hip_bfloat16* __restrict__ Wg1t, __hip_bfloat16* __restrict__ Wg2t,
    unsigned* __restrict__ bcur, int DIN, int DH, int DO, int NB) {
    const int fragTotal  = DIN * DH;
    const int fragBlocks = (fragTotal + 255) / 256;
    const int n2 = DH * DO, ng = DO * DO;
    const int smallTotal  = n2 + 2 * ng;
    const int smallBlocks = (smallTotal + 255) / 256;
    const int bid = blockIdx.x;
    if (bid < fragBlocks) {
        int tid = bid * 256 + threadIdx.x;
        if (tid >= fragTotal) return;
        int j = tid & 7, l = (tid >> 3) & 63, G = tid >> 9;
        int m = l & 15, q = l >> 4;
        int t = G & 7, kk = G >> 3;
        int n = t * 16 + m;
        int k = kk * 32 + q * 8 + j;
        W1f[tid] = __float2bfloat16(W1[k * DH + n]);
    } else if (bid < fragBlocks + smallBlocks) {
        int i = (bid - fragBlocks) * 256 + threadIdx.x;
        if (i < n2) {
            int r = i / DO, c = i % DO;
            W2t[c * DH + r] = __float2bfloat16(W2[i]);
        } else if (i < n2 + ng) {
            int j = i - n2; int r = j / DO, c = j % DO;
            Wg1t[c * DO + r] = __float2bfloat16(Wg1[j]);
        } else if (i < smallTotal) {
            int j = i - n2 - ng; int r = j / DO, c = j % DO;
            Wg2t[c * DO + r] = __float2bfloat16(Wg2[j]);
        }
    } else {
        int i = (bid - fragBlocks - smallBlocks) * 256 + threadIdx.x;
        if (i < NB) bcur[i] = 0u;
    }
}

// ---------------------------------------------------------------------------
// Scatter body (512 threads): partition edges into per-bucket regions.
// LDS hist+scan, one global atomic per (block,bucket) to reserve space,
// LDS-staged reorder, coalesced-run write-out of packed words.
// ---------------------------------------------------------------------------
struct ScatterSmem {
    unsigned stg[EPB];
    unsigned hist[512], inc[512], cur[512], start[512];
};

static __device__ __forceinline__ void scatter_body(
    int bid, ScatterSmem& sm, const int* __restrict__ src, const int* __restrict__ dst,
    unsigned* __restrict__ bcur, unsigned* __restrict__ ebuck, int E, int NB) {
    const int tid = threadIdx.x;
    sm.hist[tid] = 0u;
    __syncthreads();
    const int beg = bid * EPB;
    const int end = min(beg + EPB, E);
    for (int e = beg + tid; e < end; e += 512)
        atomicAdd(&sm.hist[((unsigned)dst[e]) >> 8], 1u);
    __syncthreads();
    const unsigned h = sm.hist[tid];
    sm.inc[tid] = h;
    __syncthreads();
    for (int off = 1; off < 512; off <<= 1) {
        unsigned t = (tid >= off) ? sm.inc[tid - off] : 0u;
        __syncthreads();
        sm.inc[tid] += t;
        __syncthreads();
    }
    sm.cur[tid] = sm.inc[tid] - h;
    if (tid < NB && h > 0u)
        sm.start[tid] = (unsigned)tid * BCAP + atomicAdd(&bcur[tid], h);
    __syncthreads();
    for (int e = beg + tid; e < end; e += 512) {
        unsigned b = ((unsigned)dst[e]) >> 8;
        unsigned r = atomicAdd(&sm.cur[b], 1u);
        sm.stg[r] = (unsigned)e;
    }
    __syncthreads();
    const int cnt = end - beg;
    for (int s = tid; s < cnt; s += 512) {
        const unsigned e = sm.stg[s];
        const unsigned d = (unsigned)dst[e];
        const unsigned b = d >> 8;
        const unsigned excl = sm.inc[b] - sm.hist[b];
        const unsigned pos = sm.start[b] + ((unsigned)s - excl);
        ebuck[pos] = (unsigned)src[e] | ((d & 255u) << 20);
    }
}

// ---------------------------------------------------------------------------
// enc1 body (512 threads, 8 waves x 16 rows = 128 rows/block):
// C[M,128] = leaky(A[M,512]@W1 + b1), A fp32, Bp fragment-ordered bf16.
// ---------------------------------------------------------------------------
static __device__ __forceinline__ void enc1_body(
    int bid, uint4 (*lds)[1024], const float* __restrict__ A, const uint4* __restrict__ Bp,
    const float* __restrict__ bias, __hip_bfloat16* __restrict__ C, int M) {
    constexpr int K = 512;
    const int tid = threadIdx.x;
    const int wid = tid >> 6, lane = tid & 63;
    const int m = lane & 15, q = lane >> 4;
    const int row0 = bid * 128 + wid * 16;
    const int rowA = row0 + m;
    const int rowAc = rowA < M ? rowA : M - 1;
    const float* Ap = A + (size_t)rowAc * K + q * 8;

    v4f32 acc[8];
#pragma unroll
    for (int t = 0; t < 8; t++) acc[t] = (v4f32){0.f, 0.f, 0.f, 0.f};

    float4 ab[2][4];

    auto loadA = [&](int c, int par) {
#pragma unroll
        for (int j = 0; j < 4; j++)
            ab[par][j] = *reinterpret_cast<const float4*>(Ap + c * 64 + (j >> 1) * 32 + (j & 1) * 4);
    };
    auto stage = [&](int c, int par) {
        lds[par][tid]       = Bp[c * 1024 + tid];
        lds[par][512 + tid] = Bp[c * 1024 + 512 + tid];
    };

    stage(0, 0);
    loadA(0, 0);
    for (int c = 0; c < 8; c++) {
        __syncthreads();
        if (c < 7) { stage(c + 1, (c + 1) & 1); loadA(c + 1, (c + 1) & 1); }
        const int par = c & 1;
#pragma unroll
        for (int kk2 = 0; kk2 < 2; kk2++) {
            float4 f0 = ab[par][kk2 * 2], f1 = ab[par][kk2 * 2 + 1];
            v8bf16 a = {(__bf16)f0.x, (__bf16)f0.y, (__bf16)f0.z, (__bf16)f0.w,
                        (__bf16)f1.x, (__bf16)f1.y, (__bf16)f1.z, (__bf16)f1.w};
#pragma unroll
            for (int t = 0; t < 8; t++) {
                v8bf16 b = reinterpret_cast<const v8bf16*>(lds[par])[(kk2 * 8 + t) * 64 + lane];
                acc[t] = __builtin_amdgcn_mfma_f32_16x16x32_bf16(a, b, acc[t], 0, 0, 0);
            }
        }
    }

#pragma unroll
    for (int r = 0; r < 4; r++) {
        const int row = row0 + q * 4 + r;
        if (row >= M) continue;
#pragma unroll
        for (int t = 0; t < 8; t++) {
            const int col = t * 16 + m;
            C[(size_t)row * 128 + col] = __float2bfloat16(leaky(acc[t][r] + bias[col]));
        }
    }
}

// ---------------------------------------------------------------------------
// L2: mega kernel = bucket_scatter (latency-bound) || gemm_enc1 (compute)
// ---------------------------------------------------------------------------
__global__ __launch_bounds__(512, 4) void mega_scatter_enc1(
    const int* __restrict__ src, const int* __restrict__ dst,
    unsigned* __restrict__ bcur, unsigned* __restrict__ ebuck, int E, int NB, int nScatter,
    const float* __restrict__ A, const uint4* __restrict__ Bp,
    const float* __restrict__ bias, __hip_bfloat16* __restrict__ C, int M) {
    union Smem {
        ScatterSmem sc;
        uint4 g[2][1024];
    };
    __shared__ Smem sm;
    const int bid = blockIdx.x;
    if (bid < nScatter) scatter_body(bid, sm.sc, src, dst, bcur, ebuck, E, NB);
    else                enc1_body(bid - nScatter, sm.g, A, Bp, bias, C, M);
}

// ---------------------------------------------------------------------------
// Small GEMM body (bf16 A): C[M,N] = A[M,K]@B, Bt[N][K] bf16.
// MODE 0: C=bf16(leaky(AB+bias));  MODE 1: C=bf16((AB)*dinv[row])
// ---------------------------------------------------------------------------
template <int NT, int MODE>
static __device__ __forceinline__ void gemm_body(
    int bid, const __hip_bfloat16* __restrict__ A, const __hip_bfloat16* __restrict__ Bt,
    const float* __restrict__ bias, const float* __restrict__ dinv,
    __hip_bfloat16* __restrict__ Cbf, int M, int K) {
    const int wid  = threadIdx.x >> 6;
    const int lane = threadIdx.x & 63;
    const int row0 = (bid * 4 + wid) << 4;
    if (row0 >= M) return;
    const int m = lane & 15, q = lane >> 4;

    const __hip_bfloat16* Ab = A + (size_t)(row0 + m) * K + q * 8;

    v4f32 acc[NT];
#pragma unroll
    for (int t = 0; t < NT; t++) acc[t] = (v4f32){0.f, 0.f, 0.f, 0.f};

    for (int k0 = 0; k0 < K; k0 += 32) {
        v8bf16 a = *reinterpret_cast<const v8bf16*>(Ab + k0);
#pragma unroll
        for (int t = 0; t < NT; t++) {
            v8bf16 b = *reinterpret_cast<const v8bf16*>(Bt + (size_t)(t * 16 + m) * K + k0 + q * 8);
            acc[t] = __builtin_amdgcn_mfma_f32_16x16x32_bf16(a, b, acc[t], 0, 0, 0);
        }
    }

    const int N = NT * 16;
#pragma unroll
    for (int r = 0; r < 4; r++) {
        const int row = row0 + q * 4 + r;
        float di = (MODE == 1) ? dinv[row] : 1.0f;
#pragma unroll
        for (int t = 0; t < NT; t++) {
            const int col = t * 16 + m;
            float v = acc[t][r];
            if (MODE == 0) v = leaky(v + bias[col]);
            else           v *= di;
            Cbf[(size_t)row * N + col] = __float2bfloat16(v);
        }
    }
}

template <int NT, int MODE>
__global__ __launch_bounds__(256) void gemm_kernel(
    const __hip_bfloat16* __restrict__ A, const __hip_bfloat16* __restrict__ Bt,
    const float* __restrict__ bias, const float* __restrict__ dinv,
    __hip_bfloat16* __restrict__ Cbf, int M, int K) {
    gemm_body<NT, MODE>(blockIdx.x, A, Bt, bias, dinv, Cbf, M, K);
}

// ---------------------------------------------------------------------------
// bucket_csr body: one block per bucket; padded CSR layout (no scan).
// rp2[node] = (beg, end) into padded csr; dinv from per-node degree.
// ---------------------------------------------------------------------------
static __device__ __forceinline__ void csr_body(
    int k, unsigned* hist, unsigned* cur, const unsigned* __restrict__ bcur,
    const unsigned* __restrict__ ebuck, uint2* __restrict__ rp2,
    float* __restrict__ dinv, int* __restrict__ csr, int NN) {
    const int tid = threadIdx.x;
    const unsigned cntb = bcur[k];
    const unsigned base = (unsigned)k * BCAP;
    const unsigned* eb = ebuck + base;
    hist[tid] = 0u;
    __syncthreads();
    for (unsigned e = tid; e < cntb; e += 256)
        atomicAdd(&hist[eb[e] >> 20], 1u);
    __syncthreads();
    const unsigned h = hist[tid];
    cur[tid] = h;
    __syncthreads();
    for (int off = 1; off < 256; off <<= 1) {
        unsigned t = (tid >= off) ? cur[tid - off] : 0u;
        __syncthreads();
        cur[tid] += t;
        __syncthreads();
    }
    const unsigned excl = cur[tid] - h;
    const int node = k * 256 + tid;
    if (node < NN) {
        rp2[node] = make_uint2(base + excl, base + excl + h);
        dinv[node] = rsqrtf((float)(h + 1u));  // +1 self-loop
    }
    __syncthreads();
    cur[tid] = excl;
    __syncthreads();
    for (unsigned e = tid; e < cntb; e += 256) {
        const unsigned pk = eb[e];
        const unsigned pos = base + atomicAdd(&cur[pk >> 20], 1u);
        csr[pos] = (int)(pk & 0xFFFFFu);
    }
}

// ---------------------------------------------------------------------------
// L3: mega kernel = bucket_csr (latency-bound) || gemm_enc2 (compute)
// ---------------------------------------------------------------------------
__global__ __launch_bounds__(256) void mega_csr_enc2(
    const unsigned* __restrict__ bcur, const unsigned* __restrict__ ebuck,
    uint2* __restrict__ rp2, float* __restrict__ dinv, int* __restrict__ csr,
    int NN, int nCsr,
    const __hip_bfloat16* __restrict__ A, const __hip_bfloat16* __restrict__ Bt,
    const float* __restrict__ bias, __hip_bfloat16* __restrict__ Cb, int M, int K) {
    __shared__ unsigned hist[256], cur[256];
    const int bid = blockIdx.x;
    if (bid < nCsr) csr_body(bid, hist, cur, bcur, ebuck, rp2, dinv, csr, NN);
    else            gemm_body<4, 0>(bid - nCsr, A, Bt, bias, nullptr, Cb, M, K);
}

// ---------------------------------------------------------------------------
// Fused CSR gather + GCN epilogue. One wave per dst node.
// 8 groups x 8 lanes, unroll-2 pipeline: 16 rows in flight per wave, next
// super-iter's indices prefetched before this super-iter's row loads.
// ---------------------------------------------------------------------------
template <int HEAD>
__global__ __launch_bounds__(256) void gather_kernel(
    const uint2* __restrict__ rp2, const int* __restrict__ csr_src,
    const __hip_bfloat16* __restrict__ u, const float* __restrict__ dinv,
    const float* __restrict__ bias, __hip_bfloat16* __restrict__ out_bf,
    float* __restrict__ out_h, const float* __restrict__ Wc,
    const float* __restrict__ bc, float* __restrict__ out_logits, int n) {
    const int node = blockIdx.x * 4 + (threadIdx.x >> 6);
    if (node >= n) return;
    const int lane = threadIdx.x & 63;
    const int g = lane >> 3, t = lane & 7;  // 8 groups x 8 lanes
    const uint2 rp = rp2[node];
    const unsigned beg = rp.x, end = rp.y;

    float s[8];
#pragma unroll
    for (int j = 0; j < 8; j++) s[j] = 0.f;

    unsigned e = beg + g;
    bool hA = e < end, hB = e + 8 < end;
    int sA = hA ? csr_src[e] : 0;
    int sB = hB ? csr_src[e + 8] : 0;
    while (hA) {
        const unsigned en = e + 16;
        const bool hA2 = en < end, hB2 = en + 8 < end;
        const int sA2 = hA2 ? csr_src[en] : 0;
        const int sB2 = hB2 ? csr_src[en + 8] : 0;
        ushort8v wA = *reinterpret_cast<const ushort8v*>(u + (size_t)sA * 64 + t * 8);
        if (hB) {
            ushort8v wB = *reinterpret_cast<const ushort8v*>(u + (size_t)sB * 64 + t * 8);
#pragma unroll
            for (int j = 0; j < 8; j++) s[j] += bfbits2f(wA[j]) + bfbits2f(wB[j]);
        } else {
#pragma unroll
            for (int j = 0; j < 8; j++) s[j] += bfbits2f(wA[j]);
        }
        e = en; hA = hA2; hB = hB2; sA = sA2; sB = sB2;
    }
    // reduce across the 8 groups (lane bits 3,4,5)
#pragma unroll
    for (int j = 0; j < 8; j++) {
        s[j] += __shfl_xor(s[j], 8, 64);
        s[j] += __shfl_xor(s[j], 16, 64);
        s[j] += __shfl_xor(s[j], 32, 64);
    }

    // self-loop row
    ushort8v wsr = *reinterpret_cast<const ushort8v*>(u + (size_t)node * 64 + t * 8);
#pragma unroll
    for (int j = 0; j < 8; j++) s[j] += bfbits2f(wsr[j]);

    const float di = dinv[node];
    const float4 b0 = *reinterpret_cast<const float4*>(bias + t * 8);
    const float4 b1 = *reinterpret_cast<const float4*>(bias + t * 8 + 4);
    float f[8];
    f[0] = leaky(s[0] * di + b0.x); f[1] = leaky(s[1] * di + b0.y);
    f[2] = leaky(s[2] * di + b0.z); f[3] = leaky(s[3] * di + b0.w);
    f[4] = leaky(s[4] * di + b1.x); f[5] = leaky(s[5] * di + b1.y);
    f[6] = leaky(s[6] * di + b1.z); f[7] = leaky(s[7] * di + b1.w);

    if (HEAD == 0) {
        if (g == 0) {
            ushort8v o;
#pragma unroll
            for (int j = 0; j < 8; j++) o[j] = f2bfbits(f[j]);
            *reinterpret_cast<ushort8v*>(out_bf + (size_t)node * 64 + t * 8) = o;
        }
    } else {
        if (g == 0) {
            float4 o0 = {f[0], f[1], f[2], f[3]};
            float4 o1 = {f[4], f[5], f[6], f[7]};
            *reinterpret_cast<float4*>(out_h + (size_t)node * 64 + t * 8) = o0;
            *reinterpret_cast<float4*>(out_h + (size_t)node * 64 + t * 8 + 4) = o1;
        }
        float p0 = 0.f, p1 = 0.f;
#pragma unroll
        for (int j = 0; j < 8; j++) {
            p0 += f[j] * Wc[(t * 8 + j) * 2];
            p1 += f[j] * Wc[(t * 8 + j) * 2 + 1];
        }
#pragma unroll
        for (int o = 4; o; o >>= 1) {
            p0 += __shfl_xor(p0, o, 64);
            p1 += __shfl_xor(p1, o, 64);
        }
        if (lane == 0) {
            out_logits[(size_t)node * 2 + 0] = p0 + bc[0];
            out_logits[(size_t)node * 2 + 1] = p1 + bc[1];
        }
    }
}

// ---------------------------------------------------------------------------
extern "C" void kernel_launch(void* const* d_in, const int* in_sizes, int n_in,
                              void* d_out, int out_size, void* d_ws, size_t ws_size,
                              hipStream_t stream) {
    const float* x   = (const float*)d_in[0];
    const int*   ei  = (const int*)d_in[1];
    const float* W1  = (const float*)d_in[2];
    const float* b1  = (const float*)d_in[3];
    const float* W2  = (const float*)d_in[4];
    const float* b2  = (const float*)d_in[5];
    const float* Wg1 = (const float*)d_in[6];
    const float* bg1 = (const float*)d_in[7];
    const float* Wg2 = (const float*)d_in[8];
    const float* bg2 = (const float*)d_in[9];
    const float* Wc  = (const float*)d_in[10];
    const float* bc  = (const float*)d_in[11];

    const int DH  = in_sizes[3];            // 128
    const int DIN = in_sizes[2] / DH;       // 512
    const int NN  = in_sizes[0] / DIN;      // 100000
    const int E   = in_sizes[1] / 2;        // 3200000
    const int DO  = in_sizes[5];            // 64
    const int* src = ei;
    const int* dst = ei + E;

    // workspace layout (~118 MB total)
    char*  ws  = (char*)d_ws;
    size_t off = 0;
    auto alloc = [&](size_t bytes) {
        void* p = ws + off;
        off += (bytes + 255) & ~(size_t)255;
        return p;
    };
    const int NB = (NN + 255) >> 8;  // 391 buckets
    __hip_bfloat16* h1    = (__hip_bfloat16*)alloc((size_t)NN * DH * 2);
    __hip_bfloat16* h2    = (__hip_bfloat16*)alloc((size_t)NN * DO * 2);
    __hip_bfloat16* h3    = (__hip_bfloat16*)alloc((size_t)NN * DO * 2);
    __hip_bfloat16* ub    = (__hip_bfloat16*)alloc((size_t)NN * DO * 2);
    float*          dinv  = (float*)alloc((size_t)NN * 4);
    uint2*          rp2   = (uint2*)alloc((size_t)NN * 8);
    int*            csr   = (int*)alloc((size_t)NB * BCAP * 4);
    unsigned*       ebuck = (unsigned*)alloc((size_t)NB * BCAP * 4);
    unsigned*       bcur  = (unsigned*)alloc(512 * 4);
    __hip_bfloat16* W1f   = (__hip_bfloat16*)alloc((size_t)DIN * DH * 2);
    __hip_bfloat16* W2t   = (__hip_bfloat16*)alloc((size_t)DH * DO * 2);
    __hip_bfloat16* Wg1t  = (__hip_bfloat16*)alloc((size_t)DO * DO * 2);
    __hip_bfloat16* Wg2t  = (__hip_bfloat16*)alloc((size_t)DO * DO * 2);

    float* out_logits = (float*)d_out;
    float* out_h      = (float*)d_out + (size_t)NN * 2;

    // L1: weight prep + cursor zero (one launch)
    const int fragBlocks  = (DIN * DH + 255) / 256;
    const int smallBlocks = (DH * DO + 2 * DO * DO + 255) / 256;
    const int zeroBlocks  = (NB + 255) / 256;
    prep_all<<<fragBlocks + smallBlocks + zeroBlocks, 256, 0, stream>>>(
        W1, W2, Wg1, Wg2, W1f, W2t, Wg1t, Wg2t, bcur, DIN, DH, DO, NB);

    // L2: bucket_scatter || gemm_enc1
    const int nblkP = (E + EPB - 1) / EPB;       // 500
    const int enc1B = (NN + 127) / 128;          // 782
    mega_scatter_enc1<<<nblkP + enc1B, 512, 0, stream>>>(
        src, dst, bcur, ebuck, E, NB, nblkP,
        x, (const uint4*)W1f, b1, h1, NN);

    // L3: bucket_csr || gemm_enc2
    const int gemm_blocks = (NN / 16 + 3) / 4;   // 1563
    mega_csr_enc2<<<NB + gemm_blocks, 256, 0, stream>>>(
        bcur, ebuck, rp2, dinv, csr, NN, NB,
        h1, W2t, b2, h2, NN, DH);

    // L4: GCN layer 1 linear: ub = (h2@Wg1)*dinv
    gemm_kernel<4, 1><<<gemm_blocks, 256, 0, stream>>>(h2, Wg1t, nullptr, dinv, ub, NN, DO);
    // L5: gather + epilogue -> h3 (bf16)
    gather_kernel<0><<<(NN + 3) / 4, 256, 0, stream>>>(rp2, csr, ub, dinv, bg1, h3,
                                                       nullptr, nullptr, nullptr, nullptr, NN);

    // L6: GCN layer 2 linear
    gemm_kernel<4, 1><<<gemm_blocks, 256, 0, stream>>>(h3, Wg2t, nullptr, dinv, ub, NN, DO);
    // L7: gather + head
    gather_kernel<1><<<(NN + 3) / 4, 256, 0, stream>>>(rp2, csr, ub, dinv, bg2, nullptr,
                                                       out_h, Wc, bc, out_logits, NN);
}